// Round 16
// baseline (136.847 us; speedup 1.0000x reference)
//
#include <hip/hip_runtime.h>
#include <hip/hip_bf16.h>
#include <stdint.h>

// Problem: B=8, T=4096, C=1024, D=128 single-head causal attention, fp32 in/out.
// Pipeline: prep_w ; qkv_gemm (m97-structure; Q pre-scaled by 1/sqrt(128)) ; attn_fwd.
// R16 attn: T15-style skewed pipeline — per iteration: stage(t+2) ; softmax+PV(t-1)
// (registers only, independent) ; QK^T(t) ; read V(t) frags. Softmax VALU and the
// P-LDS roundtrip hide under QK^T MFMA/ds_read. Geometry unchanged (16 rows/wave,
// split-KV x2, uniform 33 iters, defer-rescale, cvt_pk).

typedef __attribute__((ext_vector_type(8))) short short8;   // 8 bf16 (4 VGPRs)
typedef __attribute__((ext_vector_type(4))) float f32x4;
typedef __attribute__((ext_vector_type(4))) unsigned short u16x4;

#define NB 8
#define NT 4096
#define NC 1024
#define ND 128

__device__ __forceinline__ unsigned short f2bf(float f) {
    union { float f; uint32_t u; } v; v.f = f;
    uint32_t u = v.u;
    return (unsigned short)((u + 0x7FFFu + ((u >> 16) & 1u)) >> 16);  // RNE
}

// ---------------- W -> bf16, transposed: Wbt[w][n][k] = W_w[k][n] ----------------
__global__ void prep_w(const float* __restrict__ Wq, const float* __restrict__ Wk,
                       const float* __restrict__ Wv, unsigned short* __restrict__ Wbt) {
    int idx = blockIdx.x * 256 + threadIdx.x;          // 0 .. 3*128*1024-1
    int w = idx >> 17;                                  // 131072 per matrix
    int rem = idx & 131071;
    int n = rem >> 10;
    int k = rem & 1023;
    const float* W = (w == 0) ? Wq : (w == 1) ? Wk : Wv;
    Wbt[idx] = f2bf(W[k * ND + n]);
}

// ---------------- QKV projection, m97 structure (Q pre-scaled) ----------------
__global__ __launch_bounds__(256, 3)
void qkv_gemm(const float* __restrict__ x, const unsigned short* __restrict__ Wbt,
              unsigned short* __restrict__ Qo, unsigned short* __restrict__ Ko,
              unsigned short* __restrict__ Vto) {
    __shared__ __align__(16) float Al[128 * 64];           // 32 KB fp32, swizzled
    __shared__ __align__(16) unsigned short Bl[128 * 64];  // 16 KB bf16, swizzled
    const int mt = blockIdx.x, nt = blockIdx.y;
    const int tid = threadIdx.x;
    const int lane = tid & 63;
    const int w = tid >> 6;
    const int wr = w >> 1, wc = w & 1;
    const int l15 = lane & 15, lg = lane >> 4;
    const int m0 = mt * 128;
    const unsigned short* Wn = Wbt + (size_t)nt * (ND * NC);

    f32x4 acc[4][4];
#pragma unroll
    for (int i = 0; i < 4; ++i)
#pragma unroll
        for (int j = 0; j < 4; ++j) acc[i][j] = (f32x4)0.0f;

    for (int ks = 0; ks < 16; ++ks) {
        const int k0 = ks * 64;
#pragma unroll
        for (int r = 0; r < 8; ++r) {
            int o = r * 4096 + tid * 16;                 // linear byte offset
            int row = o >> 8;                             // 256 B per row
            int colb = (o & 255) ^ ((row & 7) << 4);
            const float* src = x + (size_t)(m0 + row) * NC + k0 + (colb >> 2);
            __builtin_amdgcn_global_load_lds(
                (const __attribute__((address_space(1))) void*)src,
                (__attribute__((address_space(3))) void*)((char*)Al + o), 16, 0, 0);
        }
#pragma unroll
        for (int r = 0; r < 4; ++r) {
            int o = r * 4096 + tid * 16;
            int row = o >> 7;                             // 128 B per row
            int colb = (o & 127) ^ ((row & 7) << 4);
            const unsigned short* src = Wn + (size_t)row * NC + k0 + (colb >> 1);
            __builtin_amdgcn_global_load_lds(
                (const __attribute__((address_space(1))) void*)src,
                (__attribute__((address_space(3))) void*)((char*)Bl + o), 16, 0, 0);
        }
        __syncthreads();                                  // drain: tiles ready

#pragma unroll
        for (int kc = 0; kc < 2; ++kc) {
            short8 a[4], b[4];
#pragma unroll
            for (int mi = 0; mi < 4; ++mi) {
                const int row = wr * 64 + mi * 16 + l15;
                const int cb = (row & 7) << 4;
                const int base = row * 256;
                f32x4 lo = *reinterpret_cast<const f32x4*>(
                    (const char*)Al + base + ((kc * 128 + lg * 32) ^ cb));
                f32x4 hi = *reinterpret_cast<const f32x4*>(
                    (const char*)Al + base + ((kc * 128 + lg * 32 + 16) ^ cb));
                short8 av;
#pragma unroll
                for (int e = 0; e < 4; ++e) {
                    av[e] = (short)f2bf(lo[e]);
                    av[4 + e] = (short)f2bf(hi[e]);
                }
                a[mi] = av;
            }
#pragma unroll
            for (int ni = 0; ni < 4; ++ni) {
                const int row = wc * 64 + ni * 16 + l15;
                const int cb = (row & 7) << 4;
                b[ni] = *reinterpret_cast<const short8*>(
                    (const char*)Bl + row * 128 + ((kc * 64 + lg * 16) ^ cb));
            }
#pragma unroll
            for (int mi = 0; mi < 4; ++mi)
#pragma unroll
                for (int ni = 0; ni < 4; ++ni)
                    acc[mi][ni] = __builtin_amdgcn_mfma_f32_16x16x32_bf16(
                        a[mi], b[ni], acc[mi][ni], 0, 0, 0);
        }
        __syncthreads();                                  // reads done before restage
    }
#pragma unroll
    for (int mi = 0; mi < 4; ++mi)
#pragma unroll
        for (int ni = 0; ni < 4; ++ni)
#pragma unroll
            for (int r = 0; r < 4; ++r) {
                int row = m0 + wr * 64 + mi * 16 + lg * 4 + r;
                int col = wc * 64 + ni * 16 + l15;
                float v = acc[mi][ni][r];
                if (nt == 0) v *= 0.08838834764831845f;   // fold 1/sqrt(d) into Q
                unsigned short bv = f2bf(v);
                if (nt == 0) Qo[(size_t)row * ND + col] = bv;
                else if (nt == 1) Ko[(size_t)row * ND + col] = bv;
                else {
                    int bb2 = row >> 12, t = row & 4095;
                    Vto[((size_t)(bb2 * ND + col)) * NT + t] = bv;
                }
            }
}

// ---------------- flash attention, causal, 8-wave split-KV x2, skewed pipeline ----------------
// 256 blocks x 512 threads; block -> (b = bid&7, p = bid>>3 in [0,32)).
// Sequential halves qt = p then 63-p; group g = w>>2 handles KV tiles t==g (mod 2),
// own double-buffered K/V LDS. Swapped QK^T -> per-lane softmax.
// Skew: iteration i = { stage(t+2) ; SM+PV(t_prev, regs only) ; QK^T(t) ; read V(t) }.
__global__ __launch_bounds__(512, 2)
void attn_fwd(const unsigned short* __restrict__ Q, const unsigned short* __restrict__ K,
              const unsigned short* __restrict__ Vt, float* __restrict__ out) {
    // [0,65536)        K: group g at g*32768, buf +buf*16384 (64x128 bf16, swizzled)
    // [65536,131072)   V: group g at 65536+g*32768, buf +buf*16384 (128x64, swizzled)
    // [131072,149504)  pw: wave w at +w*2304 (16 x 72 bf16)
    // merge (after loop, aliases dead K): O pairs at [0,32768), m/l at [32768,33280)
    __shared__ __align__(16) char smem[149504];

    const int bid = blockIdx.x;
    const int p = bid >> 3, b = bid & 7;
    const int tid = threadIdx.x;
    const int w = tid >> 6, lane = tid & 63;
    const int l15 = lane & 15, lg = lane >> 4;
    const int g = w >> 2, wq = w & 3;

    const float L2E = 1.4426950408889634f;

    unsigned short* Kg = (unsigned short*)(smem + g * 32768);
    unsigned short* Vg = (unsigned short*)(smem + 65536 + g * 32768);
    unsigned short* pw = (unsigned short*)(smem + 131072 + w * 2304);
    float* mOp = (float*)(smem) + wq * 2048;            // 16x128 f32 per pair
    float* mml = (float*)(smem + 32768) + wq * 32;      // [2][16] per pair

    const unsigned short* Kbase = &K[(size_t)b * NT * ND];
    const unsigned short* Vbase = &Vt[(size_t)b * ND * NT];

    auto stage = [&](int buf, int s0) {
#pragma unroll
        for (int r = 0; r < 4; ++r) {          // K tile: 64 rows x 256B
            int off = r * 4096 + wq * 1024 + lane * 16;
            int row = off >> 8;
            int gcol = (off & 255) ^ ((row & 7) << 4);
            const unsigned short* src = Kbase + (size_t)(s0 + row) * ND + (gcol >> 1);
            __builtin_amdgcn_global_load_lds(
                (const __attribute__((address_space(1))) void*)src,
                (__attribute__((address_space(3))) void*)(Kg + ((buf * 16384 + r * 4096 + wq * 1024) >> 1)),
                16, 0, 0);
        }
#pragma unroll
        for (int r = 0; r < 4; ++r) {          // V tile: 128 rows x 128B
            int off = r * 4096 + wq * 1024 + lane * 16;
            int row = off >> 7;
            int gcol = (off & 127) ^ ((row & 7) << 4);
            const unsigned short* src = Vbase + (size_t)row * NT + s0 + (gcol >> 1);
            __builtin_amdgcn_global_load_lds(
                (const __attribute__((address_space(1))) void*)src,
                (__attribute__((address_space(3))) void*)(Vg + ((buf * 16384 + r * 4096 + wq * 1024) >> 1)),
                16, 0, 0);
        }
    };

    for (int half = 0; half < 2; ++half) {
        const int qt = half ? (63 - p) : p;
        const int qb0 = qt * 64;
        const int qw0 = qb0 + wq * 16;
        const int niter = (qt + 2) >> 1;       // ceil((qt+1)/2)

        // Q fragments (pre-scaled by 1/sqrt(d)); lane l holds Q[m=l&15][k-chunk l>>4]
        short8 qf[4];
        const size_t qbase = ((size_t)b * NT + qw0 + l15) * ND;
#pragma unroll
        for (int c = 0; c < 4; ++c)
            qf[c] = *reinterpret_cast<const short8*>(&Q[qbase + c * 32 + lg * 8]);

        f32x4 o[8];
#pragma unroll
        for (int jn = 0; jn < 8; ++jn) o[jn] = (f32x4)0.0f;
        float mrow = -1e30f, lsum = 0.0f;      // per-lane state for q = qw0 + l15

        // pipeline state: previous tile's scores + V fragments (registers only)
        f32x4 sp[4];
        short8 vfp[16];
        int s0p = -1;

        // ---- current-tile QK^T into sp, and V frag read into vfp ----
        auto QKT = [&](const unsigned short* KlC) {
#pragma unroll
            for (int j = 0; j < 4; ++j) sp[j] = (f32x4)0.0f;
            __builtin_amdgcn_s_setprio(1);
#pragma unroll
            for (int j = 0; j < 4; ++j) {
                const int row = j * 16 + l15;
                const int cb = (row & 7) << 4;
#pragma unroll
                for (int c = 0; c < 4; ++c) {
                    short8 kf = *reinterpret_cast<const short8*>(
                        &KlC[row * 128 + (((c * 64 + lg * 16) ^ cb) >> 1)]);
                    sp[j] = __builtin_amdgcn_mfma_f32_16x16x32_bf16(kf, qf[c], sp[j], 0, 0, 0);
                }
            }
            __builtin_amdgcn_s_setprio(0);
        };
        auto readVF = [&](const unsigned short* VlC) {
#pragma unroll
            for (int jn = 0; jn < 8; ++jn) {
                const int row = jn * 16 + l15;
                const int cb = (row & 7) << 4;
#pragma unroll
                for (int kc = 0; kc < 2; ++kc)
                    vfp[jn * 2 + kc] = *reinterpret_cast<const short8*>(
                        &VlC[row * 64 + (((kc * 64 + lg * 16) ^ cb) >> 1)]);
            }
        };
        // ---- finish previous tile: softmax + pack + PV (registers only) ----
        auto SMPV = [&]() {
            const int s0c = s0p;
            const bool diag = (s0c + 64 > qw0);
            float pmax = -1e30f;
            if (diag) {
#pragma unroll
                for (int j = 0; j < 4; ++j)
#pragma unroll
                    for (int r = 0; r < 4; ++r) {
                        float sv = sp[j][r];
                        if (s0c + j * 16 + lg * 4 + r > qw0 + l15) sv = -1e30f;
                        sp[j][r] = sv;
                        pmax = fmaxf(pmax, sv);
                    }
            } else {
#pragma unroll
                for (int j = 0; j < 4; ++j)
#pragma unroll
                    for (int r = 0; r < 4; ++r)
                        pmax = fmaxf(pmax, sp[j][r]);
            }
            pmax = fmaxf(pmax, __shfl_xor(pmax, 16, 64));
            pmax = fmaxf(pmax, __shfl_xor(pmax, 32, 64));
            const bool need = (pmax > mrow + 8.0f);    // defer-rescale THR=8
            float mn = need ? pmax : mrow;
            float alpha = need ? exp2f((mrow - mn) * L2E) : 1.0f;
            mrow = mn;
            float psum = 0.0f;
#pragma unroll
            for (int j = 0; j < 4; ++j)
#pragma unroll
                for (int r = 0; r < 4; ++r) {
                    float pv = exp2f((sp[j][r] - mn) * L2E);
                    sp[j][r] = pv;
                    psum += pv;
                }
            psum += __shfl_xor(psum, 16, 64);
            psum += __shfl_xor(psum, 32, 64);
            lsum = lsum * alpha + psum;

            // P -> bf16 (cvt_pk), packed b64 LDS write, reload as A-frags
#pragma unroll
            for (int j = 0; j < 4; ++j) {
                uint2 val;
                asm("v_cvt_pk_bf16_f32 %0, %1, %2"
                    : "=v"(val.x) : "v"(sp[j][0]), "v"(sp[j][1]));
                asm("v_cvt_pk_bf16_f32 %0, %1, %2"
                    : "=v"(val.y) : "v"(sp[j][2]), "v"(sp[j][3]));
                *reinterpret_cast<uint2*>(&pw[l15 * 72 + j * 16 + lg * 4]) = val;
            }
            asm volatile("s_waitcnt lgkmcnt(0)" ::: "memory");
            short8 pa[2];
#pragma unroll
            for (int kc = 0; kc < 2; ++kc)
                pa[kc] = *reinterpret_cast<const short8*>(&pw[l15 * 72 + kc * 32 + lg * 8]);
            asm volatile("s_waitcnt lgkmcnt(0)" ::: "memory");

            if (__any((int)need)) {
                float aT[4];
#pragma unroll
                for (int r = 0; r < 4; ++r) aT[r] = __shfl(alpha, lg * 4 + r, 64);
#pragma unroll
                for (int jn = 0; jn < 8; ++jn)
#pragma unroll
                    for (int r = 0; r < 4; ++r) o[jn][r] *= aT[r];
            }

            __builtin_amdgcn_s_setprio(1);
#pragma unroll
            for (int jn = 0; jn < 8; ++jn)
#pragma unroll
                for (int kc = 0; kc < 2; ++kc)
                    o[jn] = __builtin_amdgcn_mfma_f32_16x16x32_bf16(
                        pa[kc], vfp[jn * 2 + kc], o[jn], 0, 0, 0);
            __builtin_amdgcn_s_setprio(0);
        };

        if (g <= qt) stage(0, g * 64);
        __syncthreads();                       // drains vmcnt: first tiles ready
        int cur = 0;

        for (int i = 0; i < niter; ++i) {
            const int t = 2 * i + g;
            const int s0 = t * 64;
            if (t + 2 <= qt) stage(cur ^ 1, (t + 2) * 64);

            if (s0p >= 0) SMPV();              // finish tile t-2 (regs only)

            if (t <= qt) {
                QKT(Kg + cur * 8192);          // scores for tile t
                readVF(Vg + cur * 8192);       // V frags for tile t
                s0p = s0;
            } else {
                s0p = -1;
            }

            __syncthreads();                   // prefetch done + reads drained
            cur ^= 1;
        }
        if (s0p >= 0) SMPV();                  // drain last tile

        // ---- merge: group1 publishes (m,l,O) via LDS (aliases dead K region) ----
        if (g == 1) {
#pragma unroll
            for (int jn = 0; jn < 8; ++jn)
#pragma unroll
                for (int r = 0; r < 4; ++r)
                    mOp[(lg * 4 + r) * 128 + jn * 16 + l15] = o[jn][r];
            if (lg == 0) {
                mml[l15] = mrow;
                mml[16 + l15] = lsum;
            }
        }
        __syncthreads();
        if (g == 0) {
            float e0[4], e1[4], rL[4];
#pragma unroll
            for (int r = 0; r < 4; ++r) {
                int rr = lg * 4 + r;
                float m0T = __shfl(mrow, rr, 64);
                float l0T = __shfl(lsum, rr, 64);
                float m1 = mml[rr], l1 = mml[16 + rr];
                float M = fmaxf(m0T, m1);
                e0[r] = exp2f((m0T - M) * L2E);
                e1[r] = exp2f((m1 - M) * L2E);
                rL[r] = 1.0f / (l0T * e0[r] + l1 * e1[r]);
            }
#pragma unroll
            for (int jn = 0; jn < 8; ++jn)
#pragma unroll
                for (int r = 0; r < 4; ++r) {
                    int rr = lg * 4 + r, cc = jn * 16 + l15;
                    float v = o[jn][r] * e0[r] + mOp[rr * 128 + cc] * e1[r];
                    out[((size_t)b * NT + qw0 + rr) * ND + cc] = v * rL[r];
                }
        }
        __syncthreads();                       // merge reads done before restaging
    }
}

extern "C" void kernel_launch(void* const* d_in, const int* in_sizes, int n_in,
                              void* d_out, int out_size, void* d_ws, size_t ws_size,
                              hipStream_t stream) {
    const float* x  = (const float*)d_in[0];
    const float* Wq = (const float*)d_in[1];
    const float* Wk = (const float*)d_in[2];
    const float* Wv = (const float*)d_in[3];
    float* out = (float*)d_out;

    unsigned short* ws  = (unsigned short*)d_ws;
    unsigned short* Wbt = ws;                               // 3*128*1024
    unsigned short* Qb  = Wbt + 3 * ND * NC;                // 8*4096*128 (pre-scaled)
    unsigned short* Kb  = Qb + (size_t)NB * NT * ND;
    unsigned short* Vtb = Kb + (size_t)NB * NT * ND;        // transposed [B][D][T]

    prep_w<<<1536, 256, 0, stream>>>(Wq, Wk, Wv, Wbt);
    qkv_gemm<<<dim3(256, 3), 256, 0, stream>>>(x, Wbt, Qb, Kb, Vtb);
    attn_fwd<<<256, 512, 0, stream>>>(Qb, Kb, Vtb, out);
}

// Round 17
// 123.085 us; speedup vs baseline: 1.1118x; 1.1118x over previous
//
#include <hip/hip_runtime.h>
#include <hip/hip_bf16.h>
#include <stdint.h>

// Problem: B=8, T=4096, C=1024, D=128 single-head causal attention, fp32 in/out.
// Pipeline: prep_w ; qkv_gemm (R17: FUSED single pass over x — one block computes
// Q,K,V for a 64-row x tile; all 3 W^T k-slices staged in LDS; x read once) ;
// attn_fwd (R15 structure: 16 q-rows/wave, split-KV x2, swapped QK^T, per-lane
// softmax, cvt_pk, defer-rescale; R16 skew reverted).

typedef __attribute__((ext_vector_type(8))) short short8;   // 8 bf16 (4 VGPRs)
typedef __attribute__((ext_vector_type(4))) float f32x4;
typedef __attribute__((ext_vector_type(4))) unsigned short u16x4;

#define NB 8
#define NT 4096
#define NC 1024
#define ND 128

__device__ __forceinline__ unsigned short f2bf(float f) {
    union { float f; uint32_t u; } v; v.f = f;
    uint32_t u = v.u;
    return (unsigned short)((u + 0x7FFFu + ((u >> 16) & 1u)) >> 16);  // RNE
}

// ---------------- W -> bf16, transposed: Wbt[w][n][k] = W_w[k][n] ----------------
__global__ void prep_w(const float* __restrict__ Wq, const float* __restrict__ Wk,
                       const float* __restrict__ Wv, unsigned short* __restrict__ Wbt) {
    int idx = blockIdx.x * 256 + threadIdx.x;          // 0 .. 3*128*1024-1
    int w = idx >> 17;                                  // 131072 per matrix
    int rem = idx & 131071;
    int n = rem >> 10;
    int k = rem & 1023;
    const float* W = (w == 0) ? Wq : (w == 1) ? Wk : Wv;
    Wbt[idx] = f2bf(W[k * ND + n]);
}

// ---------------- fused QKV projection: x read ONCE ----------------
// grid 512: blockIdx.x = 64-row M-tile. LDS: A 64x64 fp32 (16KB) + B 3x128x64
// bf16 (48KB) = 64KB -> 2 blocks/CU. K-step 64, global_load_lds staging with
// XOR swizzle (pre-swizzled source + swizzled read). Q pre-scaled by 1/sqrt(d).
__global__ __launch_bounds__(256, 2)
void qkv_gemm(const float* __restrict__ x, const unsigned short* __restrict__ Wbt,
              unsigned short* __restrict__ Qo, unsigned short* __restrict__ Ko,
              unsigned short* __restrict__ Vto) {
    __shared__ __align__(16) float Al[64 * 64];            // 16 KB fp32, swizzled
    __shared__ __align__(16) unsigned short Bl[3 * 128 * 64]; // 48 KB bf16, swizzled
    const int mt = blockIdx.x;
    const int tid = threadIdx.x;
    const int lane = tid & 63;
    const int w = tid >> 6;
    const int wr = w >> 1, wc = w & 1;
    const int l15 = lane & 15, lg = lane >> 4;
    const int m0 = mt * 64;

    f32x4 acc[3][2][4];
#pragma unroll
    for (int nt = 0; nt < 3; ++nt)
#pragma unroll
        for (int mi = 0; mi < 2; ++mi)
#pragma unroll
            for (int ni = 0; ni < 4; ++ni) acc[nt][mi][ni] = (f32x4)0.0f;

    for (int ks = 0; ks < 16; ++ks) {
        const int k0 = ks * 64;
        // ---- stage A: 64 rows x 64 k fp32 (16 KB), 4 rounds ----
#pragma unroll
        for (int r = 0; r < 4; ++r) {
            int o = r * 4096 + tid * 16;                 // linear byte offset
            int row = o >> 8;                             // 256 B per row
            int colb = (o & 255) ^ ((row & 7) << 4);
            const float* src = x + (size_t)(m0 + row) * NC + k0 + (colb >> 2);
            __builtin_amdgcn_global_load_lds(
                (const __attribute__((address_space(1))) void*)src,
                (__attribute__((address_space(3))) void*)((char*)Al + o), 16, 0, 0);
        }
        // ---- stage B: 3 x (128 rows x 64 k bf16) = 48 KB, 12 rounds ----
#pragma unroll
        for (int r = 0; r < 12; ++r) {
            int o = r * 4096 + tid * 16;
            int nt = o >> 14;                             // 16384 B per matrix
            int within = o & 16383;
            int row = within >> 7;                        // 128 B per row
            int colb = (within & 127) ^ ((row & 7) << 4);
            const unsigned short* src = Wbt + (size_t)nt * (ND * NC)
                                      + (size_t)row * NC + k0 + (colb >> 1);
            __builtin_amdgcn_global_load_lds(
                (const __attribute__((address_space(1))) void*)src,
                (__attribute__((address_space(3))) void*)((char*)Bl + o), 16, 0, 0);
        }
        __syncthreads();                                  // drain: tiles ready

#pragma unroll
        for (int kc = 0; kc < 2; ++kc) {
            short8 a[2];
#pragma unroll
            for (int mi = 0; mi < 2; ++mi) {
                const int row = wr * 32 + mi * 16 + l15;
                const int cb = (row & 7) << 4;
                const int base = row * 256;
                f32x4 lo = *reinterpret_cast<const f32x4*>(
                    (const char*)Al + base + ((kc * 128 + lg * 32) ^ cb));
                f32x4 hi = *reinterpret_cast<const f32x4*>(
                    (const char*)Al + base + ((kc * 128 + lg * 32 + 16) ^ cb));
                short8 av;
#pragma unroll
                for (int e = 0; e < 4; ++e) {
                    av[e] = (short)f2bf(lo[e]);
                    av[4 + e] = (short)f2bf(hi[e]);
                }
                a[mi] = av;
            }
#pragma unroll
            for (int nt = 0; nt < 3; ++nt)
#pragma unroll
                for (int ni = 0; ni < 4; ++ni) {
                    const int row = wc * 64 + ni * 16 + l15;
                    const int cb = (row & 7) << 4;
                    short8 bb = *reinterpret_cast<const short8*>(
                        (const char*)Bl + nt * 16384 + row * 128
                        + ((kc * 64 + lg * 16) ^ cb));
                    acc[nt][0][ni] = __builtin_amdgcn_mfma_f32_16x16x32_bf16(
                        a[0], bb, acc[nt][0][ni], 0, 0, 0);
                    acc[nt][1][ni] = __builtin_amdgcn_mfma_f32_16x16x32_bf16(
                        a[1], bb, acc[nt][1][ni], 0, 0, 0);
                }
        }
        __syncthreads();                                  // reads done before restage
    }
    // ---- epilogue: C/D layout col=lane&15, row=(lane>>4)*4+reg ----
#pragma unroll
    for (int nt = 0; nt < 3; ++nt)
#pragma unroll
        for (int mi = 0; mi < 2; ++mi)
#pragma unroll
            for (int ni = 0; ni < 4; ++ni)
#pragma unroll
                for (int r = 0; r < 4; ++r) {
                    int row = m0 + wr * 32 + mi * 16 + lg * 4 + r;
                    int col = wc * 64 + ni * 16 + l15;
                    float v = acc[nt][mi][ni][r];
                    if (nt == 0) v *= 0.08838834764831845f;   // fold 1/sqrt(d) into Q
                    unsigned short bv = f2bf(v);
                    if (nt == 0) Qo[(size_t)row * ND + col] = bv;
                    else if (nt == 1) Ko[(size_t)row * ND + col] = bv;
                    else {
                        int bb2 = row >> 12, t = row & 4095;
                        Vto[((size_t)(bb2 * ND + col)) * NT + t] = bv;
                    }
                }
}

// ---------------- flash attention, causal, 8-wave split-KV x2, swapped QK^T (R15) ----------------
// 256 blocks x 512 threads; block -> (b = bid&7, p = bid>>3 in [0,32)).
// Sequential halves qt = p then 63-p (uniform 33 iterations); group g = w>>2
// handles KV tiles t==g (mod 2), own double-buffered K/V LDS. Swapped QK^T ->
// per-lane softmax (2 shuffles). cvt_pk P conversion; defer-rescale THR=8.
__global__ __launch_bounds__(512, 2)
void attn_fwd(const unsigned short* __restrict__ Q, const unsigned short* __restrict__ K,
              const unsigned short* __restrict__ Vt, float* __restrict__ out) {
    // [0,65536)        K: group g at g*32768, buf +buf*16384 (64x128 bf16, swizzled)
    // [65536,131072)   V: group g at 65536+g*32768, buf +buf*16384 (128x64, swizzled)
    // [131072,149504)  pw: wave w at +w*2304 (16 x 72 bf16)
    // merge (after loop, aliases dead K): O pairs at [0,32768), m/l at [32768,33280)
    __shared__ __align__(16) char smem[149504];

    const int bid = blockIdx.x;
    const int p = bid >> 3, b = bid & 7;
    const int tid = threadIdx.x;
    const int w = tid >> 6, lane = tid & 63;
    const int l15 = lane & 15, lg = lane >> 4;
    const int g = w >> 2, wq = w & 3;

    const float L2E = 1.4426950408889634f;

    unsigned short* Kg = (unsigned short*)(smem + g * 32768);
    unsigned short* Vg = (unsigned short*)(smem + 65536 + g * 32768);
    unsigned short* pw = (unsigned short*)(smem + 131072 + w * 2304);
    float* mOp = (float*)(smem) + wq * 2048;            // 16x128 f32 per pair
    float* mml = (float*)(smem + 32768) + wq * 32;      // [2][16] per pair

    const unsigned short* Kbase = &K[(size_t)b * NT * ND];
    const unsigned short* Vbase = &Vt[(size_t)b * ND * NT];

    auto stage = [&](int buf, int s0) {
#pragma unroll
        for (int r = 0; r < 4; ++r) {          // K tile: 64 rows x 256B
            int off = r * 4096 + wq * 1024 + lane * 16;
            int row = off >> 8;
            int gcol = (off & 255) ^ ((row & 7) << 4);
            const unsigned short* src = Kbase + (size_t)(s0 + row) * ND + (gcol >> 1);
            __builtin_amdgcn_global_load_lds(
                (const __attribute__((address_space(1))) void*)src,
                (__attribute__((address_space(3))) void*)(Kg + ((buf * 16384 + r * 4096 + wq * 1024) >> 1)),
                16, 0, 0);
        }
#pragma unroll
        for (int r = 0; r < 4; ++r) {          // V tile: 128 rows x 128B
            int off = r * 4096 + wq * 1024 + lane * 16;
            int row = off >> 7;
            int gcol = (off & 127) ^ ((row & 7) << 4);
            const unsigned short* src = Vbase + (size_t)row * NT + s0 + (gcol >> 1);
            __builtin_amdgcn_global_load_lds(
                (const __attribute__((address_space(1))) void*)src,
                (__attribute__((address_space(3))) void*)(Vg + ((buf * 16384 + r * 4096 + wq * 1024) >> 1)),
                16, 0, 0);
        }
    };

    for (int half = 0; half < 2; ++half) {
        const int qt = half ? (63 - p) : p;
        const int qb0 = qt * 64;
        const int qw0 = qb0 + wq * 16;
        const int niter = (qt + 2) >> 1;       // ceil((qt+1)/2)

        // Q fragments (pre-scaled by 1/sqrt(d)); lane l holds Q[m=l&15][k-chunk l>>4]
        short8 qf[4];
        const size_t qbase = ((size_t)b * NT + qw0 + l15) * ND;
#pragma unroll
        for (int c = 0; c < 4; ++c)
            qf[c] = *reinterpret_cast<const short8*>(&Q[qbase + c * 32 + lg * 8]);

        f32x4 o[8];
#pragma unroll
        for (int jn = 0; jn < 8; ++jn) o[jn] = (f32x4)0.0f;
        float mrow = -1e30f, lsum = 0.0f;      // per-lane state for q = qw0 + l15

        if (g <= qt) stage(0, g * 64);
        __syncthreads();                       // drains vmcnt: first tiles ready
        int cur = 0;

        for (int i = 0; i < niter; ++i) {
            const int t = 2 * i + g;
            const int s0 = t * 64;
            if (t + 2 <= qt) stage(cur ^ 1, (t + 2) * 64);

            if (t <= qt) {
                // ---- S^T = K Q^T from Kg[cur] (swapped operands) ----
                const unsigned short* KlC = Kg + cur * 8192;
                f32x4 s[4];
#pragma unroll
                for (int j = 0; j < 4; ++j) s[j] = (f32x4)0.0f;
                __builtin_amdgcn_s_setprio(1);
#pragma unroll
                for (int j = 0; j < 4; ++j) {
                    const int row = j * 16 + l15;
                    const int cb = (row & 7) << 4;
#pragma unroll
                    for (int c = 0; c < 4; ++c) {
                        short8 kf = *reinterpret_cast<const short8*>(
                            &KlC[row * 128 + (((c * 64 + lg * 16) ^ cb) >> 1)]);
                        s[j] = __builtin_amdgcn_mfma_f32_16x16x32_bf16(kf, qf[c], s[j], 0, 0, 0);
                    }
                }
                __builtin_amdgcn_s_setprio(0);

                // ---- prefetch V half (jn=0..3) from LDS: hides under softmax ----
                const unsigned short* VlC = Vg + cur * 8192;
                short8 vf0[8];
#pragma unroll
                for (int jn = 0; jn < 4; ++jn) {
                    const int row = jn * 16 + l15;
                    const int cb = (row & 7) << 4;
#pragma unroll
                    for (int kc = 0; kc < 2; ++kc)
                        vf0[jn * 2 + kc] = *reinterpret_cast<const short8*>(
                            &VlC[row * 64 + (((kc * 64 + lg * 16) ^ cb) >> 1)]);
                }

                // ---- softmax (online), lane owns q = qw0 + l15; Q pre-scaled ----
                const bool diag = (s0 + 64 > qw0);
                float pmax = -1e30f;
                if (diag) {
#pragma unroll
                    for (int j = 0; j < 4; ++j)
#pragma unroll
                        for (int r = 0; r < 4; ++r) {
                            float sv = s[j][r];
                            if (s0 + j * 16 + lg * 4 + r > qw0 + l15) sv = -1e30f;
                            s[j][r] = sv;
                            pmax = fmaxf(pmax, sv);
                        }
                } else {
#pragma unroll
                    for (int j = 0; j < 4; ++j)
#pragma unroll
                        for (int r = 0; r < 4; ++r)
                            pmax = fmaxf(pmax, s[j][r]);
                }
                pmax = fmaxf(pmax, __shfl_xor(pmax, 16, 64));
                pmax = fmaxf(pmax, __shfl_xor(pmax, 32, 64));
                const bool need = (pmax > mrow + 8.0f);    // defer-rescale THR=8
                float mn = need ? pmax : mrow;
                float alpha = need ? exp2f((mrow - mn) * L2E) : 1.0f;
                mrow = mn;
                float psum = 0.0f;
#pragma unroll
                for (int j = 0; j < 4; ++j)
#pragma unroll
                    for (int r = 0; r < 4; ++r) {
                        float pv = exp2f((s[j][r] - mn) * L2E);
                        s[j][r] = pv;
                        psum += pv;
                    }
                psum += __shfl_xor(psum, 16, 64);
                psum += __shfl_xor(psum, 32, 64);
                lsum = lsum * alpha + psum;

                // ---- P -> bf16 via v_cvt_pk (1 op per pair), packed b64 LDS write ----
#pragma unroll
                for (int j = 0; j < 4; ++j) {
                    uint2 val;
                    asm("v_cvt_pk_bf16_f32 %0, %1, %2"
                        : "=v"(val.x) : "v"(s[j][0]), "v"(s[j][1]));
                    asm("v_cvt_pk_bf16_f32 %0, %1, %2"
                        : "=v"(val.y) : "v"(s[j][2]), "v"(s[j][3]));
                    *reinterpret_cast<uint2*>(&pw[l15 * 72 + j * 16 + lg * 4]) = val;
                }
                asm volatile("s_waitcnt lgkmcnt(0)" ::: "memory");
                short8 pa[2];
#pragma unroll
                for (int kc = 0; kc < 2; ++kc)
                    pa[kc] = *reinterpret_cast<const short8*>(&pw[l15 * 72 + kc * 32 + lg * 8]);
                asm volatile("s_waitcnt lgkmcnt(0)" ::: "memory");

                // ---- rescale O only when some row's max actually grew ----
                if (__any((int)need)) {
                    float aT[4];
#pragma unroll
                    for (int r = 0; r < 4; ++r) aT[r] = __shfl(alpha, lg * 4 + r, 64);
#pragma unroll
                    for (int jn = 0; jn < 8; ++jn)
#pragma unroll
                        for (int r = 0; r < 4; ++r) o[jn][r] *= aT[r];
                }

                // ---- O += P V : half 0 from prefetched regs, half 1 from LDS ----
                __builtin_amdgcn_s_setprio(1);
#pragma unroll
                for (int jn = 0; jn < 4; ++jn)
#pragma unroll
                    for (int kc = 0; kc < 2; ++kc)
                        o[jn] = __builtin_amdgcn_mfma_f32_16x16x32_bf16(
                            pa[kc], vf0[jn * 2 + kc], o[jn], 0, 0, 0);
#pragma unroll
                for (int jn = 4; jn < 8; ++jn) {
                    const int row = jn * 16 + l15;
                    const int cb = (row & 7) << 4;
#pragma unroll
                    for (int kc = 0; kc < 2; ++kc) {
                        short8 vf = *reinterpret_cast<const short8*>(
                            &VlC[row * 64 + (((kc * 64 + lg * 16) ^ cb) >> 1)]);
                        o[jn] = __builtin_amdgcn_mfma_f32_16x16x32_bf16(pa[kc], vf, o[jn], 0, 0, 0);
                    }
                }
                __builtin_amdgcn_s_setprio(0);
            }

            __syncthreads();                   // prefetch done + reads drained
            cur ^= 1;
        }

        // ---- merge: group1 publishes (m,l,O) via LDS (aliases dead K region) ----
        if (g == 1) {
#pragma unroll
            for (int jn = 0; jn < 8; ++jn)
#pragma unroll
                for (int r = 0; r < 4; ++r)
                    mOp[(lg * 4 + r) * 128 + jn * 16 + l15] = o[jn][r];
            if (lg == 0) {
                mml[l15] = mrow;
                mml[16 + l15] = lsum;
            }
        }
        __syncthreads();
        if (g == 0) {
            float e0[4], e1[4], rL[4];
#pragma unroll
            for (int r = 0; r < 4; ++r) {
                int rr = lg * 4 + r;
                float m0T = __shfl(mrow, rr, 64);
                float l0T = __shfl(lsum, rr, 64);
                float m1 = mml[rr], l1 = mml[16 + rr];
                float M = fmaxf(m0T, m1);
                e0[r] = exp2f((m0T - M) * L2E);
                e1[r] = exp2f((m1 - M) * L2E);
                rL[r] = 1.0f / (l0T * e0[r] + l1 * e1[r]);
            }
#pragma unroll
            for (int jn = 0; jn < 8; ++jn)
#pragma unroll
                for (int r = 0; r < 4; ++r) {
                    int rr = lg * 4 + r, cc = jn * 16 + l15;
                    float v = o[jn][r] * e0[r] + mOp[rr * 128 + cc] * e1[r];
                    out[((size_t)b * NT + qw0 + rr) * ND + cc] = v * rL[r];
                }
        }
        __syncthreads();                       // merge reads done before restaging
    }
}

extern "C" void kernel_launch(void* const* d_in, const int* in_sizes, int n_in,
                              void* d_out, int out_size, void* d_ws, size_t ws_size,
                              hipStream_t stream) {
    const float* x  = (const float*)d_in[0];
    const float* Wq = (const float*)d_in[1];
    const float* Wk = (const float*)d_in[2];
    const float* Wv = (const float*)d_in[3];
    float* out = (float*)d_out;

    unsigned short* ws  = (unsigned short*)d_ws;
    unsigned short* Wbt = ws;                               // 3*128*1024
    unsigned short* Qb  = Wbt + 3 * ND * NC;                // 8*4096*128 (pre-scaled)
    unsigned short* Kb  = Qb + (size_t)NB * NT * ND;
    unsigned short* Vtb = Kb + (size_t)NB * NT * ND;        // transposed [B][D][T]

    prep_w<<<1536, 256, 0, stream>>>(Wq, Wk, Wv, Wbt);
    qkv_gemm<<<512, 256, 0, stream>>>(x, Wbt, Qb, Kb, Vtb);
    attn_fwd<<<256, 512, 0, stream>>>(Qb, Kb, Vtb, out);
}